// Round 1
// baseline (102.143 us; speedup 1.0000x reference)
//
#include <hip/hip_runtime.h>
#include <hip/hip_bf16.h>

typedef float f32x4 __attribute__((ext_vector_type(4)));
typedef short bf16x8 __attribute__((ext_vector_type(8)));

#define LRELU_SLOPE 0.2f
#define SQRT2F 1.4142135623730951f
#define MODSCALE 0.044194173824159216f  // 512^-0.5

// ---------------- kernel 1: style  s[b][ci] ----------------
__global__ __launch_bounds__(64) void style_kernel(const float* __restrict__ y,
                                                   const float* __restrict__ mw,
                                                   const float* __restrict__ bias,
                                                   float* __restrict__ s) {
  int ci = blockIdx.x;      // 512 blocks
  int l = threadIdx.x;      // 64 lanes
  const float4* mwr = reinterpret_cast<const float4*>(mw + ci * 512);
  float4 m0 = mwr[2 * l], m1 = mwr[2 * l + 1];
  float acc[8];
#pragma unroll
  for (int b = 0; b < 8; ++b) {
    const float4* yr = reinterpret_cast<const float4*>(y + b * 512);
    float4 y0 = yr[2 * l], y1 = yr[2 * l + 1];
    acc[b] = m0.x * y0.x + m0.y * y0.y + m0.z * y0.z + m0.w * y0.w +
             m1.x * y1.x + m1.y * y1.y + m1.z * y1.z + m1.w * y1.w;
  }
#pragma unroll
  for (int off = 32; off > 0; off >>= 1) {
#pragma unroll
    for (int b = 0; b < 8; ++b) acc[b] += __shfl_xor(acc[b], off, 64);
  }
  if (l < 8) {
    float v = acc[l] * MODSCALE + bias[ci];
    v = v > 0.f ? v : LRELU_SLOPE * v;
    s[l * 512 + ci] = v * SQRT2F;
  }
}

// ---------------- kernel 2: weight prep: wt[t][co][ci] bf16 + wsq[co][ci] ----------------
__global__ __launch_bounds__(256) void wprep_kernel(const float* __restrict__ w,
                                                    __hip_bfloat16* __restrict__ wt,
                                                    float* __restrict__ wsq) {
  int idx = blockIdx.x * 256 + threadIdx.x;  // 262144 = co*512+ci
  const float* p = w + (size_t)idx * 9;
  float v[9];
  float sq = 0.f;
#pragma unroll
  for (int t = 0; t < 9; ++t) {
    v[t] = p[t];
    sq += v[t] * v[t];
  }
  wsq[idx] = sq;
#pragma unroll
  for (int t = 0; t < 9; ++t) wt[t * 262144 + idx] = __float2bfloat16(v[t]);
}

// ---------------- kernel 3: demod  d[b][co] ----------------
__global__ __launch_bounds__(64) void demod_kernel(const float* __restrict__ wsq,
                                                   const float* __restrict__ s,
                                                   float* __restrict__ d) {
  int co = blockIdx.x;  // 512 blocks
  int l = threadIdx.x;
  const float4* qr = reinterpret_cast<const float4*>(wsq + co * 512);
  float4 q0 = qr[2 * l], q1 = qr[2 * l + 1];
  float acc[8];
#pragma unroll
  for (int b = 0; b < 8; ++b) {
    const float4* sr = reinterpret_cast<const float4*>(s + b * 512);
    float4 s0 = sr[2 * l], s1 = sr[2 * l + 1];
    acc[b] = q0.x * s0.x * s0.x + q0.y * s0.y * s0.y + q0.z * s0.z * s0.z +
             q0.w * s0.w * s0.w + q1.x * s1.x * s1.x + q1.y * s1.y * s1.y +
             q1.z * s1.z * s1.z + q1.w * s1.w * s1.w;
  }
#pragma unroll
  for (int off = 32; off > 0; off >>= 1) {
#pragma unroll
    for (int b = 0; b < 8; ++b) acc[b] += __shfl_xor(acc[b], off, 64);
  }
  if (l < 8) d[l * 512 + co] = rsqrtf(acc[l] + 1e-8f);
}

// ---------------- kernel 4: xs prep: NCHW f32 -> padded NHWC bf16, x * s ----------------
__global__ __launch_bounds__(256) void xs_kernel(const float* __restrict__ x,
                                                 const float* __restrict__ s,
                                                 __hip_bfloat16* __restrict__ xsp) {
  // grid: b(8) * h(32) * cc(8) = 2048 blocks of 256
  int bid = blockIdx.x;
  int cc = bid & 7;
  int h = (bid >> 3) & 31;
  int b = bid >> 8;
  int tid = threadIdx.x;
  __shared__ __hip_bfloat16 tile[32][72];  // [w][ci_local], padded

  int cil = tid >> 2;            // 0..63
  int w0 = (tid & 3) * 8;        // 0,8,16,24
  int ci = cc * 64 + cil;
  const float* xp = x + (((size_t)(b * 512 + ci) * 32 + h) << 5) + w0;
  float sv = s[b * 512 + ci];
  float4 a0 = *reinterpret_cast<const float4*>(xp);
  float4 a1 = *reinterpret_cast<const float4*>(xp + 4);
  tile[w0 + 0][cil] = __float2bfloat16(a0.x * sv);
  tile[w0 + 1][cil] = __float2bfloat16(a0.y * sv);
  tile[w0 + 2][cil] = __float2bfloat16(a0.z * sv);
  tile[w0 + 3][cil] = __float2bfloat16(a0.w * sv);
  tile[w0 + 4][cil] = __float2bfloat16(a1.x * sv);
  tile[w0 + 5][cil] = __float2bfloat16(a1.y * sv);
  tile[w0 + 6][cil] = __float2bfloat16(a1.z * sv);
  tile[w0 + 7][cil] = __float2bfloat16(a1.w * sv);
  __syncthreads();

  int wloc = tid >> 3;           // 0..31
  int cj = (tid & 7) * 8;        // 0..56
  int4 v = *reinterpret_cast<const int4*>(&tile[wloc][cj]);
  unsigned off = (unsigned)((b * 34 + h + 1) * 34 + (wloc + 1)) * 512 + cc * 64 + cj;
  *reinterpret_cast<int4*>(xsp + off) = v;
}

// ---------------- kernel 5: the conv (implicit GEMM, MFMA bf16) ----------------
// A ("pixels") = xs_p [b][34][34][512] bf16 ; B ("weights") = wt [t][co][ci] bf16
// D[co][pix] via swapped operands; per-block tile 128 pix x 128 co, BK=64, 9 taps.
__global__ __launch_bounds__(256) void conv_kernel(const __hip_bfloat16* __restrict__ xsp,
                                                   const __hip_bfloat16* __restrict__ wt,
                                                   const float* __restrict__ dmod,
                                                   float* __restrict__ out) {
  __shared__ __hip_bfloat16 As[128 * 64];
  __shared__ __hip_bfloat16 Bs[128 * 64];
  const int bid = blockIdx.x;  // 256 = 64 m-tiles * 4 n-tiles
  const int bm = bid >> 2;
  const int bn = bid & 3;
  const int tid = threadIdx.x;
  const int wv = tid >> 6;
  const int l = tid & 63;
  const int wr = wv >> 1;
  const int wc = wv & 1;
  const int bb = bm >> 3;  // batch index (8 m-tiles per batch)

  // staging: wave-chunk c = j*4+wv covers rows 8c..8c+7; lane l -> row 8c+(l>>3),
  // physical 16B-chunk (l&7). XOR-swizzle st: physical p holds logical p^(row&7),
  // row&7 == l>>3 at staging time -> fetch logical chunk (l&7)^(l>>3).
  const int swz8 = (((l & 7) ^ (l >> 3)) << 3);  // element offset
  unsigned aoff[4], boff[4];
#pragma unroll
  for (int j = 0; j < 4; ++j) {
    int p = ((j * 4 + wv) << 3) + (l >> 3);
    int m = (bm << 7) + p;
    int hh = (m >> 5) & 31;
    int ww = m & 31;
    aoff[j] = (unsigned)((bb * 34 + hh) * 34 + ww) * 512 + swz8;
    int co = (bn << 7) + ((j * 4 + wv) << 3) + (l >> 3);
    boff[j] = (unsigned)co * 512 + swz8;
  }

  f32x4 acc[4][4];
#pragma unroll
  for (int n = 0; n < 4; ++n)
#pragma unroll
    for (int m = 0; m < 4; ++m) acc[n][m] = (f32x4)0.f;

  for (int t = 0; t < 9; ++t) {
    const unsigned tapoff = (unsigned)((t / 3) * 34 + (t % 3)) * 512;
    const unsigned wtoff = (unsigned)t * 262144u;
#pragma unroll 1
    for (int k0 = 0; k0 < 512; k0 += 64) {
#pragma unroll
      for (int j = 0; j < 4; ++j) {
        __builtin_amdgcn_global_load_lds(
            (const __attribute__((address_space(1))) unsigned int*)(xsp + aoff[j] + tapoff + k0),
            (__attribute__((address_space(3))) unsigned int*)(As + ((j * 4 + wv) << 9)),
            16, 0, 0);
      }
#pragma unroll
      for (int j = 0; j < 4; ++j) {
        __builtin_amdgcn_global_load_lds(
            (const __attribute__((address_space(1))) unsigned int*)(wt + wtoff + boff[j] + k0),
            (__attribute__((address_space(3))) unsigned int*)(Bs + ((j * 4 + wv) << 9)),
            16, 0, 0);
      }
      __syncthreads();
#pragma unroll
      for (int kk = 0; kk < 2; ++kk) {
        const int pos = (((kk * 4 + (l >> 4)) ^ (l & 7)) << 3);  // swizzled read
        bf16x8 af[4], bfr[4];
#pragma unroll
        for (int m = 0; m < 4; ++m)
          af[m] = *reinterpret_cast<const bf16x8*>(
              As + (((wr << 6) + (m << 4) + (l & 15)) << 6) + pos);
#pragma unroll
        for (int n = 0; n < 4; ++n)
          bfr[n] = *reinterpret_cast<const bf16x8*>(
              Bs + (((wc << 6) + (n << 4) + (l & 15)) << 6) + pos);
#pragma unroll
        for (int n = 0; n < 4; ++n)
#pragma unroll
          for (int m = 0; m < 4; ++m)
            acc[n][m] = __builtin_amdgcn_mfma_f32_16x16x32_bf16(bfr[n], af[m], acc[n][m], 0, 0, 0);
      }
      __syncthreads();
    }
  }

  // epilogue: D[co][pix]; row(co) = (l>>4)*4 + jj, col(pix) = l&15 -> 64B-contig stores
  const int pixbase = ((bm & 7) << 7) + (wr << 6) + (l & 15);
  const int cob = (bn << 7) + (wc << 6) + ((l >> 4) << 2);
  float* ob = out + ((size_t)bb << 19);
  const float* drow = dmod + bb * 512;
#pragma unroll
  for (int n = 0; n < 4; ++n) {
#pragma unroll
    for (int jj = 0; jj < 4; ++jj) {
      const int co = cob + (n << 4) + jj;
      const float dv = drow[co];
      float* orow = ob + ((unsigned)co << 10) + pixbase;
#pragma unroll
      for (int m = 0; m < 4; ++m) orow[m << 4] = acc[n][m][jj] * dv;
    }
  }
}

extern "C" void kernel_launch(void* const* d_in, const int* in_sizes, int n_in,
                              void* d_out, int out_size, void* d_ws, size_t ws_size,
                              hipStream_t stream) {
  (void)in_sizes; (void)n_in; (void)out_size; (void)ws_size;
  const float* x = (const float*)d_in[0];       // [8,512,32,32]
  const float* y = (const float*)d_in[1];       // [8,512]
  const float* w = (const float*)d_in[2];       // [512,512,3,3]
  const float* mw = (const float*)d_in[3];      // [512,512]
  const float* bias = (const float*)d_in[4];    // [512]
  float* out = (float*)d_out;                   // [8,512,32,32]

  char* ws = (char*)d_ws;
  float* s = (float*)(ws + 0);                  // 16 KB
  float* dmod = (float*)(ws + 16384);           // 16 KB
  float* wsq = (float*)(ws + 32768);            // 1 MB
  __hip_bfloat16* wt = (__hip_bfloat16*)(ws + 1081344);    // 9*512*512*2 = 4.5 MB
  __hip_bfloat16* xsp = (__hip_bfloat16*)(ws + 5799936);   // 8*34*34*512*2 = 9.03 MB

  hipMemsetAsync(xsp, 0, 9469952, stream);  // zero padded borders
  style_kernel<<<512, 64, 0, stream>>>(y, mw, bias, s);
  wprep_kernel<<<1024, 256, 0, stream>>>(w, wt, wsq);
  demod_kernel<<<512, 64, 0, stream>>>(wsq, s, dmod);
  xs_kernel<<<2048, 256, 0, stream>>>(x, s, xsp);
  conv_kernel<<<256, 256, 0, stream>>>(xsp, wt, dmod, out);
}

// Round 3
// 101.655 us; speedup vs baseline: 1.0048x; 1.0048x over previous
//
#include <hip/hip_runtime.h>
#include <hip/hip_bf16.h>

typedef float f32x4 __attribute__((ext_vector_type(4)));
typedef short bf16x8 __attribute__((ext_vector_type(8)));

#define LRELU_SLOPE 0.2f
#define SQRT2F 1.4142135623730951f
#define MODSCALE 0.044194173824159216f  // 512^-0.5

// ---------------- kernel 1: style  s[b][ci] ----------------
__global__ __launch_bounds__(64) void style_kernel(const float* __restrict__ y,
                                                   const float* __restrict__ mw,
                                                   const float* __restrict__ bias,
                                                   float* __restrict__ s) {
  int ci = blockIdx.x;      // 512 blocks
  int l = threadIdx.x;      // 64 lanes
  const float4* mwr = reinterpret_cast<const float4*>(mw + ci * 512);
  float4 m0 = mwr[2 * l], m1 = mwr[2 * l + 1];
  float acc[8];
#pragma unroll
  for (int b = 0; b < 8; ++b) {
    const float4* yr = reinterpret_cast<const float4*>(y + b * 512);
    float4 y0 = yr[2 * l], y1 = yr[2 * l + 1];
    acc[b] = m0.x * y0.x + m0.y * y0.y + m0.z * y0.z + m0.w * y0.w +
             m1.x * y1.x + m1.y * y1.y + m1.z * y1.z + m1.w * y1.w;
  }
#pragma unroll
  for (int off = 32; off > 0; off >>= 1) {
#pragma unroll
    for (int b = 0; b < 8; ++b) acc[b] += __shfl_xor(acc[b], off, 64);
  }
  if (l < 8) {
    float v = acc[l] * MODSCALE + bias[ci];
    v = v > 0.f ? v : LRELU_SLOPE * v;
    s[l * 512 + ci] = v * SQRT2F;
  }
}

// ---------------- kernel 2: weight prep: wt[t][co][ci] bf16 + wsq[co][ci] ----------------
__global__ __launch_bounds__(256) void wprep_kernel(const float* __restrict__ w,
                                                    __hip_bfloat16* __restrict__ wt,
                                                    float* __restrict__ wsq) {
  int idx = blockIdx.x * 256 + threadIdx.x;  // 262144 = co*512+ci
  const float* p = w + (size_t)idx * 9;
  float v[9];
  float sq = 0.f;
#pragma unroll
  for (int t = 0; t < 9; ++t) {
    v[t] = p[t];
    sq += v[t] * v[t];
  }
  wsq[idx] = sq;
#pragma unroll
  for (int t = 0; t < 9; ++t) wt[t * 262144 + idx] = __float2bfloat16(v[t]);
}

// ---------------- kernel 3: demod  d[b][co] ----------------
__global__ __launch_bounds__(64) void demod_kernel(const float* __restrict__ wsq,
                                                   const float* __restrict__ s,
                                                   float* __restrict__ d) {
  int co = blockIdx.x;  // 512 blocks
  int l = threadIdx.x;
  const float4* qr = reinterpret_cast<const float4*>(wsq + co * 512);
  float4 q0 = qr[2 * l], q1 = qr[2 * l + 1];
  float acc[8];
#pragma unroll
  for (int b = 0; b < 8; ++b) {
    const float4* sr = reinterpret_cast<const float4*>(s + b * 512);
    float4 s0 = sr[2 * l], s1 = sr[2 * l + 1];
    acc[b] = q0.x * s0.x * s0.x + q0.y * s0.y * s0.y + q0.z * s0.z * s0.z +
             q0.w * s0.w * s0.w + q1.x * s1.x * s1.x + q1.y * s1.y * s1.y +
             q1.z * s1.z * s1.z + q1.w * s1.w * s1.w;
  }
#pragma unroll
  for (int off = 32; off > 0; off >>= 1) {
#pragma unroll
    for (int b = 0; b < 8; ++b) acc[b] += __shfl_xor(acc[b], off, 64);
  }
  if (l < 8) d[l * 512 + co] = rsqrtf(acc[l] + 1e-8f);
}

// ---------------- kernel 4: xs prep: NCHW f32 -> padded NHWC bf16, x * s ----------------
__global__ __launch_bounds__(256) void xs_kernel(const float* __restrict__ x,
                                                 const float* __restrict__ s,
                                                 __hip_bfloat16* __restrict__ xsp) {
  // grid: b(8) * h(32) * cc(8) = 2048 blocks of 256
  int bid = blockIdx.x;
  int cc = bid & 7;
  int h = (bid >> 3) & 31;
  int b = bid >> 8;
  int tid = threadIdx.x;
  __shared__ __hip_bfloat16 tile[32][72];  // [w][ci_local], padded

  int cil = tid >> 2;            // 0..63
  int w0 = (tid & 3) * 8;        // 0,8,16,24
  int ci = cc * 64 + cil;
  const float* xp = x + (((size_t)(b * 512 + ci) * 32 + h) << 5) + w0;
  float sv = s[b * 512 + ci];
  float4 a0 = *reinterpret_cast<const float4*>(xp);
  float4 a1 = *reinterpret_cast<const float4*>(xp + 4);
  tile[w0 + 0][cil] = __float2bfloat16(a0.x * sv);
  tile[w0 + 1][cil] = __float2bfloat16(a0.y * sv);
  tile[w0 + 2][cil] = __float2bfloat16(a0.z * sv);
  tile[w0 + 3][cil] = __float2bfloat16(a0.w * sv);
  tile[w0 + 4][cil] = __float2bfloat16(a1.x * sv);
  tile[w0 + 5][cil] = __float2bfloat16(a1.y * sv);
  tile[w0 + 6][cil] = __float2bfloat16(a1.z * sv);
  tile[w0 + 7][cil] = __float2bfloat16(a1.w * sv);
  __syncthreads();

  int wloc = tid >> 3;           // 0..31
  int cj = (tid & 7) * 8;        // 0..56
  int4 v = *reinterpret_cast<const int4*>(&tile[wloc][cj]);
  unsigned off = (unsigned)((b * 34 + h + 1) * 34 + (wloc + 1)) * 512 + cc * 64 + cj;
  *reinterpret_cast<int4*>(xsp + off) = v;
}

// ---------------- kernel 5: the conv (implicit GEMM, MFMA bf16, pipelined) ----------------
// A ("pixels") = xs_p [b][34][34][512] bf16 ; B ("weights") = wt [t][co][ci] bf16
// D[co][pix] via swapped operands; per-block tile 128 pix x 128 co.
// K-loop: 9 taps x 8 k0-steps = 72 flat iterations, triple-buffered LDS,
// 2-deep prefetch with counted vmcnt(8) (never drained to 0 in the loop).
__global__ __launch_bounds__(256) void conv_kernel(const __hip_bfloat16* __restrict__ xsp,
                                                   const __hip_bfloat16* __restrict__ wt,
                                                   const float* __restrict__ dmod,
                                                   float* __restrict__ out) {
  __shared__ __hip_bfloat16 As[3][128 * 64];
  __shared__ __hip_bfloat16 Bs[3][128 * 64];
  const int bid = blockIdx.x;  // 256 = 64 m-tiles * 4 n-tiles
  const int bm = bid >> 2;
  const int bn = bid & 3;
  const int tid = threadIdx.x;
  const int wv = tid >> 6;
  const int l = tid & 63;
  const int wr = wv >> 1;
  const int wc = wv & 1;
  const int bb = bm >> 3;  // batch index (8 m-tiles per batch)

  // staging: wave-chunk c = j*4+wv covers rows 8c..8c+7; lane l -> row 8c+(l>>3),
  // physical 16B-chunk (l&7). XOR-swizzle: physical p holds logical p^(row&7),
  // row&7 == l>>3 at staging time -> fetch logical chunk (l&7)^(l>>3).
  const int swz8 = (((l & 7) ^ (l >> 3)) << 3);  // element offset
  unsigned aoff[4], boff[4];
#pragma unroll
  for (int j = 0; j < 4; ++j) {
    int p = ((j * 4 + wv) << 3) + (l >> 3);
    int m = (bm << 7) + p;
    int hh = (m >> 5) & 31;
    int ww = m & 31;
    aoff[j] = (unsigned)((bb * 34 + hh) * 34 + ww) * 512 + swz8;
    int co = (bn << 7) + ((j * 4 + wv) << 3) + (l >> 3);
    boff[j] = (unsigned)co * 512 + swz8;
  }

  f32x4 acc[4][4];
#pragma unroll
  for (int n = 0; n < 4; ++n)
#pragma unroll
    for (int m = 0; m < 4; ++m) acc[n][m] = (f32x4)0.f;

  // stage K-step ksn (= tap*8 + k0/64) into buffer slot st
  auto stage = [&](int ksn, int st) {
    int tt = ksn >> 3;
    int k0 = (ksn & 7) << 6;
    int dh = tt / 3;
    unsigned tap = (unsigned)(dh * 34 + (tt - 3 * dh)) * 512u;
    const __hip_bfloat16* ab = xsp + tap + k0;
    const __hip_bfloat16* bb_ = wt + ((unsigned)tt << 18) + k0;
#pragma unroll
    for (int j = 0; j < 4; ++j)
      __builtin_amdgcn_global_load_lds(
          (const __attribute__((address_space(1))) unsigned int*)(ab + aoff[j]),
          (__attribute__((address_space(3))) unsigned int*)(&As[st][(j * 4 + wv) << 9]),
          16, 0, 0);
#pragma unroll
    for (int j = 0; j < 4; ++j)
      __builtin_amdgcn_global_load_lds(
          (const __attribute__((address_space(1))) unsigned int*)(bb_ + boff[j]),
          (__attribute__((address_space(3))) unsigned int*)(&Bs[st][(j * 4 + wv) << 9]),
          16, 0, 0);
  };

  // prologue: fill buffers 0 and 1
  stage(0, 0);
  stage(1, 1);

  int rd = 0;
#pragma unroll 1
  for (int ks = 0; ks < 72; ++ks) {
    // my loads for buffer rd (issued 2 iters ago) must be done; 8 newer stay in flight
    if (ks < 71)
      asm volatile("s_waitcnt vmcnt(8)" ::: "memory");
    else
      asm volatile("s_waitcnt vmcnt(0)" ::: "memory");
    __builtin_amdgcn_s_barrier();          // all waves' loads for rd now visible
    __builtin_amdgcn_sched_barrier(0);     // pin: nothing crosses the barrier
    if (ks + 2 < 72) {
      int st = rd == 0 ? 2 : rd - 1;       // (ks+2)%3
      stage(ks + 2, st);
    }
#pragma unroll
    for (int kk = 0; kk < 2; ++kk) {
      const int pos = (((kk * 4 + (l >> 4)) ^ (l & 7)) << 3);  // swizzled read
      bf16x8 af[4], bfr[4];
#pragma unroll
      for (int m = 0; m < 4; ++m)
        af[m] = *reinterpret_cast<const bf16x8*>(
            &As[rd][(((wr << 6) + (m << 4) + (l & 15)) << 6) + pos]);
#pragma unroll
      for (int n = 0; n < 4; ++n)
        bfr[n] = *reinterpret_cast<const bf16x8*>(
            &Bs[rd][(((wc << 6) + (n << 4) + (l & 15)) << 6) + pos]);
#pragma unroll
      for (int n = 0; n < 4; ++n)
#pragma unroll
        for (int m = 0; m < 4; ++m)
          acc[n][m] = __builtin_amdgcn_mfma_f32_16x16x32_bf16(bfr[n], af[m], acc[n][m], 0, 0, 0);
    }
    rd = rd == 2 ? 0 : rd + 1;
  }

  // epilogue: D[co][pix]; row(co) = (l>>4)*4 + jj, col(pix) = l&15 -> 64B-contig stores
  const int pixbase = ((bm & 7) << 7) + (wr << 6) + (l & 15);
  const int cob = (bn << 7) + (wc << 6) + ((l >> 4) << 2);
  float* ob = out + ((size_t)bb << 19);
  const float* drow = dmod + bb * 512;
#pragma unroll
  for (int n = 0; n < 4; ++n) {
#pragma unroll
    for (int jj = 0; jj < 4; ++jj) {
      const int co = cob + (n << 4) + jj;
      const float dv = drow[co];
      float* orow = ob + ((unsigned)co << 10) + pixbase;
#pragma unroll
      for (int m = 0; m < 4; ++m) orow[m << 4] = acc[n][m][jj] * dv;
    }
  }
}

extern "C" void kernel_launch(void* const* d_in, const int* in_sizes, int n_in,
                              void* d_out, int out_size, void* d_ws, size_t ws_size,
                              hipStream_t stream) {
  (void)in_sizes; (void)n_in; (void)out_size; (void)ws_size;
  const float* x = (const float*)d_in[0];       // [8,512,32,32]
  const float* y = (const float*)d_in[1];       // [8,512]
  const float* w = (const float*)d_in[2];       // [512,512,3,3]
  const float* mw = (const float*)d_in[3];      // [512,512]
  const float* bias = (const float*)d_in[4];    // [512]
  float* out = (float*)d_out;                   // [8,512,32,32]

  char* ws = (char*)d_ws;
  float* s = (float*)(ws + 0);                  // 16 KB
  float* dmod = (float*)(ws + 16384);           // 16 KB
  float* wsq = (float*)(ws + 32768);            // 1 MB
  __hip_bfloat16* wt = (__hip_bfloat16*)(ws + 1081344);    // 9*512*512*2 = 4.5 MB
  __hip_bfloat16* xsp = (__hip_bfloat16*)(ws + 5799936);   // 8*34*34*512*2 = 9.03 MB

  hipMemsetAsync(xsp, 0, 9469952, stream);  // zero padded borders
  style_kernel<<<512, 64, 0, stream>>>(y, mw, bias, s);
  wprep_kernel<<<1024, 256, 0, stream>>>(w, wt, wsq);
  demod_kernel<<<512, 64, 0, stream>>>(wsq, s, dmod);
  xs_kernel<<<2048, 256, 0, stream>>>(x, s, xsp);
  conv_kernel<<<256, 256, 0, stream>>>(xsp, wt, dmod, out);
}

// Round 4
// 90.198 us; speedup vs baseline: 1.1324x; 1.1270x over previous
//
#include <hip/hip_runtime.h>
#include <hip/hip_bf16.h>

typedef float f32x4 __attribute__((ext_vector_type(4)));
typedef short bf16x8 __attribute__((ext_vector_type(8)));

#define LRELU_SLOPE 0.2f
#define SQRT2F 1.4142135623730951f
#define MODSCALE 0.044194173824159216f  // 512^-0.5

#define GLL(SRC, DST)                                                       \
  __builtin_amdgcn_global_load_lds(                                         \
      (const __attribute__((address_space(1))) unsigned int*)(SRC),         \
      (__attribute__((address_space(3))) unsigned int*)(DST), 16, 0, 0)

// ---------------- kernel 1: style  s[b][ci] ----------------
__global__ __launch_bounds__(64) void style_kernel(const float* __restrict__ y,
                                                   const float* __restrict__ mw,
                                                   const float* __restrict__ bias,
                                                   float* __restrict__ s) {
  int ci = blockIdx.x;      // 512 blocks
  int l = threadIdx.x;      // 64 lanes
  const float4* mwr = reinterpret_cast<const float4*>(mw + ci * 512);
  float4 m0 = mwr[2 * l], m1 = mwr[2 * l + 1];
  float acc[8];
#pragma unroll
  for (int b = 0; b < 8; ++b) {
    const float4* yr = reinterpret_cast<const float4*>(y + b * 512);
    float4 y0 = yr[2 * l], y1 = yr[2 * l + 1];
    acc[b] = m0.x * y0.x + m0.y * y0.y + m0.z * y0.z + m0.w * y0.w +
             m1.x * y1.x + m1.y * y1.y + m1.z * y1.z + m1.w * y1.w;
  }
#pragma unroll
  for (int off = 32; off > 0; off >>= 1) {
#pragma unroll
    for (int b = 0; b < 8; ++b) acc[b] += __shfl_xor(acc[b], off, 64);
  }
  if (l < 8) {
    float v = acc[l] * MODSCALE + bias[ci];
    v = v > 0.f ? v : LRELU_SLOPE * v;
    s[l * 512 + ci] = v * SQRT2F;
  }
}

// ---------------- kernel 2: weight prep: wt[t][co][ci] bf16 + wsq[co][ci] ----------------
__global__ __launch_bounds__(256) void wprep_kernel(const float* __restrict__ w,
                                                    __hip_bfloat16* __restrict__ wt,
                                                    float* __restrict__ wsq) {
  int idx = blockIdx.x * 256 + threadIdx.x;  // 262144 = co*512+ci
  const float* p = w + (size_t)idx * 9;
  float v[9];
  float sq = 0.f;
#pragma unroll
  for (int t = 0; t < 9; ++t) {
    v[t] = p[t];
    sq += v[t] * v[t];
  }
  wsq[idx] = sq;
#pragma unroll
  for (int t = 0; t < 9; ++t) wt[t * 262144 + idx] = __float2bfloat16(v[t]);
}

// ---------------- kernel 3: demod  d[b][co] ----------------
__global__ __launch_bounds__(64) void demod_kernel(const float* __restrict__ wsq,
                                                   const float* __restrict__ s,
                                                   float* __restrict__ d) {
  int co = blockIdx.x;  // 512 blocks
  int l = threadIdx.x;
  const float4* qr = reinterpret_cast<const float4*>(wsq + co * 512);
  float4 q0 = qr[2 * l], q1 = qr[2 * l + 1];
  float acc[8];
#pragma unroll
  for (int b = 0; b < 8; ++b) {
    const float4* sr = reinterpret_cast<const float4*>(s + b * 512);
    float4 s0 = sr[2 * l], s1 = sr[2 * l + 1];
    acc[b] = q0.x * s0.x * s0.x + q0.y * s0.y * s0.y + q0.z * s0.z * s0.z +
             q0.w * s0.w * s0.w + q1.x * s1.x * s1.x + q1.y * s1.y * s1.y +
             q1.z * s1.z * s1.z + q1.w * s1.w * s1.w;
  }
#pragma unroll
  for (int off = 32; off > 0; off >>= 1) {
#pragma unroll
    for (int b = 0; b < 8; ++b) acc[b] += __shfl_xor(acc[b], off, 64);
  }
  if (l < 8) d[l * 512 + co] = rsqrtf(acc[l] + 1e-8f);
}

// ---------------- kernel 4: xs prep: NCHW f32 -> padded NHWC bf16, x * s ----------------
__global__ __launch_bounds__(256) void xs_kernel(const float* __restrict__ x,
                                                 const float* __restrict__ s,
                                                 __hip_bfloat16* __restrict__ xsp) {
  // grid: b(8) * h(32) * cc(8) = 2048 blocks of 256
  int bid = blockIdx.x;
  int cc = bid & 7;
  int h = (bid >> 3) & 31;
  int b = bid >> 8;
  int tid = threadIdx.x;
  __shared__ __hip_bfloat16 tile[32][72];  // [w][ci_local], padded

  int cil = tid >> 2;            // 0..63
  int w0 = (tid & 3) * 8;        // 0,8,16,24
  int ci = cc * 64 + cil;
  const float* xp = x + (((size_t)(b * 512 + ci) * 32 + h) << 5) + w0;
  float sv = s[b * 512 + ci];
  float4 a0 = *reinterpret_cast<const float4*>(xp);
  float4 a1 = *reinterpret_cast<const float4*>(xp + 4);
  tile[w0 + 0][cil] = __float2bfloat16(a0.x * sv);
  tile[w0 + 1][cil] = __float2bfloat16(a0.y * sv);
  tile[w0 + 2][cil] = __float2bfloat16(a0.z * sv);
  tile[w0 + 3][cil] = __float2bfloat16(a0.w * sv);
  tile[w0 + 4][cil] = __float2bfloat16(a1.x * sv);
  tile[w0 + 5][cil] = __float2bfloat16(a1.y * sv);
  tile[w0 + 6][cil] = __float2bfloat16(a1.z * sv);
  tile[w0 + 7][cil] = __float2bfloat16(a1.w * sv);
  __syncthreads();

  int wloc = tid >> 3;           // 0..31
  int cj = (tid & 7) * 8;        // 0..56
  int4 v = *reinterpret_cast<const int4*>(&tile[wloc][cj]);
  unsigned off = (unsigned)((b * 34 + h + 1) * 34 + (wloc + 1)) * 512 + cc * 64 + cj;
  *reinterpret_cast<int4*>(xsp + off) = v;
}

// ---------------- kernel 5: conv — halo-reuse implicit GEMM, 9-phase counted pipeline ----
// A-halo: 6x34 positions x 64 ci staged ONCE per K-chunk (all 9 taps read from LDS).
// B: wt[t][128co][64ci] slices, double-buffered, distance-1 prefetch.
// Per K-chunk: 9 tap-phases; waits: vmcnt(0) at t=0/8, vmcnt(1) else (in-order VMEM queue).
__global__ __launch_bounds__(256) void conv_kernel(const __hip_bfloat16* __restrict__ xsp,
                                                   const __hip_bfloat16* __restrict__ wt,
                                                   const float* __restrict__ dmod,
                                                   float* __restrict__ out) {
  __shared__ __hip_bfloat16 As_[2][224 * 64];  // 204 halo rows used, padded to 224
  __shared__ __hip_bfloat16 Bs_[2][128 * 64];
  const int bid = blockIdx.x;  // 256 blocks
  // XCD-aware remap: XCD (= bid&7) hosts 8 consecutive bm values x all 4 bn
  const int xcd = bid & 7, slot = bid >> 3;
  const int bm = xcd * 8 + (slot >> 2);
  const int bn = slot & 3;
  const int tid = threadIdx.x;
  const int wv = tid >> 6;
  const int l = tid & 63;
  const int wr = wv >> 1, wc = wv & 1;
  const int bb = bm >> 3;          // batch
  const int h0 = (bm & 7) << 2;    // first output image row of this tile

  // ---- staging offsets (lane-resolved, XOR-pre-swizzled global source) ----
  const int swzB = (((l & 7) ^ (l >> 3)) << 3);
  unsigned boff[4];
#pragma unroll
  for (int j = 0; j < 4; ++j) {
    int row = (((j << 2) + wv) << 3) + (l >> 3);  // row&7 == l>>3
    boff[j] = (unsigned)((bn << 7) + row) * 512 + swzB;
  }
  unsigned ahoff[7];
#pragma unroll
  for (int j = 0; j < 7; ++j) {
    int r = j * 32 + wv * 8 + (l >> 3);  // halo row 0..223 (204..223 = safe garbage)
    int rc = r > 203 ? 203 : r;
    int hr = rc / 34, hc = rc - hr * 34;
    ahoff[j] = (unsigned)((bb * 34 + h0 + hr) * 34 + hc) * 512 + (((l & 7) ^ (r & 7)) << 3);
  }
  int pb[4];
#pragma unroll
  for (int m = 0; m < 4; ++m)
    pb[m] = ((wr << 1) + (m >> 1)) * 34 + ((m & 1) << 4) + (l & 15);

  f32x4 acc[4][4];
#pragma unroll
  for (int n = 0; n < 4; ++n)
#pragma unroll
    for (int m = 0; m < 4; ++m) acc[n][m] = (f32x4)0.f;

  auto stageB = [&](__hip_bfloat16* Bn, int t, int k0c) {
    const __hip_bfloat16* src = wt + t * 262144 + k0c * 64;
#pragma unroll
    for (int j = 0; j < 4; ++j)
      GLL(src + boff[j], Bn + (((((j << 2) + wv) << 3)) << 6));
  };
  auto stageA1 = [&](__hip_bfloat16* An, int j, int kn) {
    GLL(xsp + ahoff[j] + kn * 64, An + (j * 32 + wv * 8) * 64);
  };
  auto phase = [&](const __hip_bfloat16* Aq, const __hip_bfloat16* Bq, int dh, int dw) {
#pragma unroll
    for (int kk = 0; kk < 2; ++kk) {
      const int cb = (kk << 2) + (l >> 4);
      bf16x8 af[4], bfr[4];
#pragma unroll
      for (int m = 0; m < 4; ++m) {
        int p = pb[m] + dh * 34 + dw;
        af[m] = *reinterpret_cast<const bf16x8*>(Aq + p * 64 + ((cb ^ (p & 7)) << 3));
      }
#pragma unroll
      for (int n = 0; n < 4; ++n) {
        int row = (wc << 6) + (n << 4) + (l & 15);
        bfr[n] = *reinterpret_cast<const bf16x8*>(Bq + row * 64 + ((cb ^ (l & 7)) << 3));
      }
#pragma unroll
      for (int n = 0; n < 4; ++n)
#pragma unroll
        for (int m = 0; m < 4; ++m)
          acc[n][m] = __builtin_amdgcn_mfma_f32_16x16x32_bf16(bfr[n], af[m], acc[n][m], 0, 0, 0);
    }
  };

#define WAITBAR(N)                                          \
  asm volatile("s_waitcnt vmcnt(" #N ")" ::: "memory");     \
  __builtin_amdgcn_s_barrier();                             \
  __builtin_amdgcn_sched_barrier(0)

  // prologue: A halo for k0=0 (7 chunks), then B(t=0, k0=0)
#pragma unroll
  for (int j = 0; j < 7; ++j) stageA1(&As_[0][0], j, 0);
  __builtin_amdgcn_sched_barrier(0);
  stageB(&Bs_[0][0], 0, 0);

#pragma unroll 1
  for (int k0 = 0; k0 < 7; ++k0) {  // steady K-chunks
    const int a = k0 & 1;
    const __hip_bfloat16* Aq = &As_[a][0];
    __hip_bfloat16* An = &As_[a ^ 1][0];
    // t = 0
    WAITBAR(0);
    stageB(&Bs_[(k0 + 1) & 1][0], 1, k0);
    __builtin_amdgcn_sched_barrier(0);
    stageA1(An, 0, k0 + 1);
    phase(Aq, &Bs_[k0 & 1][0], 0, 0);
    // t = 1..6
#pragma unroll
    for (int t = 1; t <= 6; ++t) {
      WAITBAR(1);
      stageB(&Bs_[(k0 + t + 1) & 1][0], t + 1, k0);
      __builtin_amdgcn_sched_barrier(0);
      stageA1(An, t, k0 + 1);
      phase(Aq, &Bs_[(k0 + t) & 1][0], t / 3, t % 3);
    }
    // t = 7
    WAITBAR(1);
    stageB(&Bs_[(k0 + 8) & 1][0], 8, k0);
    phase(Aq, &Bs_[(k0 + 7) & 1][0], 2, 1);
    // t = 8
    WAITBAR(0);
    stageB(&Bs_[(k0 + 9) & 1][0], 0, k0 + 1);
    phase(Aq, &Bs_[(k0 + 8) & 1][0], 2, 2);
  }
  {  // k0 = 7 (drain chunk, no further A/B-next staging)
    const __hip_bfloat16* Aq = &As_[1][0];
#pragma unroll
    for (int t = 0; t <= 7; ++t) {
      WAITBAR(0);
      stageB(&Bs_[(7 + t + 1) & 1][0], t + 1, 7);
      phase(Aq, &Bs_[(7 + t) & 1][0], t / 3, t % 3);
    }
    WAITBAR(0);
    phase(Aq, &Bs_[1][0], 2, 2);
  }
#undef WAITBAR

  // epilogue: D[co][pix]; row(co) = (l>>4)*4 + jj, col(pix) = l&15 -> 64B-contig stores
  const int pixbase = ((bm & 7) << 7) + (wr << 6) + (l & 15);
  const int cob = (bn << 7) + (wc << 6) + ((l >> 4) << 2);
  float* ob = out + ((size_t)bb << 19);
  const float* drow = dmod + bb * 512;
#pragma unroll
  for (int n = 0; n < 4; ++n) {
#pragma unroll
    for (int jj = 0; jj < 4; ++jj) {
      const int co = cob + (n << 4) + jj;
      const float dv = drow[co];
      float* orow = ob + ((unsigned)co << 10) + pixbase;
#pragma unroll
      for (int m = 0; m < 4; ++m) orow[m << 4] = acc[n][m][jj] * dv;
    }
  }
}

extern "C" void kernel_launch(void* const* d_in, const int* in_sizes, int n_in,
                              void* d_out, int out_size, void* d_ws, size_t ws_size,
                              hipStream_t stream) {
  (void)in_sizes; (void)n_in; (void)out_size; (void)ws_size;
  const float* x = (const float*)d_in[0];       // [8,512,32,32]
  const float* y = (const float*)d_in[1];       // [8,512]
  const float* w = (const float*)d_in[2];       // [512,512,3,3]
  const float* mw = (const float*)d_in[3];      // [512,512]
  const float* bias = (const float*)d_in[4];    // [512]
  float* out = (float*)d_out;                   // [8,512,32,32]

  char* ws = (char*)d_ws;
  float* s = (float*)(ws + 0);                  // 16 KB
  float* dmod = (float*)(ws + 16384);           // 16 KB
  float* wsq = (float*)(ws + 32768);            // 1 MB
  __hip_bfloat16* wt = (__hip_bfloat16*)(ws + 1081344);    // 9*512*512*2 = 4.5 MB
  __hip_bfloat16* xsp = (__hip_bfloat16*)(ws + 5799936);   // 8*34*34*512*2 = 9.03 MB

  hipMemsetAsync(xsp, 0, 9469952, stream);  // zero padded borders
  style_kernel<<<512, 64, 0, stream>>>(y, mw, bias, s);
  wprep_kernel<<<1024, 256, 0, stream>>>(w, wt, wsq);
  demod_kernel<<<512, 64, 0, stream>>>(wsq, s, dmod);
  xs_kernel<<<2048, 256, 0, stream>>>(x, s, xsp);
  conv_kernel<<<256, 256, 0, stream>>>(xsp, wt, dmod, out);
}

// Round 7
// 68.477 us; speedup vs baseline: 1.4917x; 1.3172x over previous
//
#include <hip/hip_runtime.h>
#include <hip/hip_bf16.h>

typedef float f32x4 __attribute__((ext_vector_type(4)));
typedef short bf16x8 __attribute__((ext_vector_type(8)));

#define LRELU_SLOPE 0.2f
#define SQRT2F 1.4142135623730951f
#define MODSCALE 0.044194173824159216f  // 512^-0.5

#define GLL(SRC, DST)                                                       \
  __builtin_amdgcn_global_load_lds(                                         \
      (const __attribute__((address_space(1))) unsigned int*)(SRC),         \
      (__attribute__((address_space(3))) unsigned int*)(DST), 16, 0, 0)

// ---------------- kernel 1: style  s[b][ci] ----------------
__global__ __launch_bounds__(64) void style_kernel(const float* __restrict__ y,
                                                   const float* __restrict__ mw,
                                                   const float* __restrict__ bias,
                                                   float* __restrict__ s) {
  int ci = blockIdx.x;      // 512 blocks
  int l = threadIdx.x;      // 64 lanes
  const float4* mwr = reinterpret_cast<const float4*>(mw + ci * 512);
  float4 m0 = mwr[2 * l], m1 = mwr[2 * l + 1];
  float acc[8];
#pragma unroll
  for (int b = 0; b < 8; ++b) {
    const float4* yr = reinterpret_cast<const float4*>(y + b * 512);
    float4 y0 = yr[2 * l], y1 = yr[2 * l + 1];
    acc[b] = m0.x * y0.x + m0.y * y0.y + m0.z * y0.z + m0.w * y0.w +
             m1.x * y1.x + m1.y * y1.y + m1.z * y1.z + m1.w * y1.w;
  }
#pragma unroll
  for (int off = 32; off > 0; off >>= 1) {
#pragma unroll
    for (int b = 0; b < 8; ++b) acc[b] += __shfl_xor(acc[b], off, 64);
  }
  if (l < 8) {
    float v = acc[l] * MODSCALE + bias[ci];
    v = v > 0.f ? v : LRELU_SLOPE * v;
    s[l * 512 + ci] = v * SQRT2F;
  }
}

// ---------------- kernel 2: weight prep: wt[t][co][ci] bf16 + wsq[co][ci] ----------------
__global__ __launch_bounds__(256) void wprep_kernel(const float* __restrict__ w,
                                                    __hip_bfloat16* __restrict__ wt,
                                                    float* __restrict__ wsq) {
  int idx = blockIdx.x * 256 + threadIdx.x;  // 262144 = co*512+ci
  const float* p = w + (size_t)idx * 9;
  float v[9];
  float sq = 0.f;
#pragma unroll
  for (int t = 0; t < 9; ++t) {
    v[t] = p[t];
    sq += v[t] * v[t];
  }
  wsq[idx] = sq;
#pragma unroll
  for (int t = 0; t < 9; ++t) wt[t * 262144 + idx] = __float2bfloat16(v[t]);
}

// ---------------- kernel 3: demod  d[b][co] ----------------
__global__ __launch_bounds__(64) void demod_kernel(const float* __restrict__ wsq,
                                                   const float* __restrict__ s,
                                                   float* __restrict__ d) {
  int co = blockIdx.x;  // 512 blocks
  int l = threadIdx.x;
  const float4* qr = reinterpret_cast<const float4*>(wsq + co * 512);
  float4 q0 = qr[2 * l], q1 = qr[2 * l + 1];
  float acc[8];
#pragma unroll
  for (int b = 0; b < 8; ++b) {
    const float4* sr = reinterpret_cast<const float4*>(s + b * 512);
    float4 s0 = sr[2 * l], s1 = sr[2 * l + 1];
    acc[b] = q0.x * s0.x * s0.x + q0.y * s0.y * s0.y + q0.z * s0.z * s0.z +
             q0.w * s0.w * s0.w + q1.x * s1.x * s1.x + q1.y * s1.y * s1.y +
             q1.z * s1.z * s1.z + q1.w * s1.w * s1.w;
  }
#pragma unroll
  for (int off = 32; off > 0; off >>= 1) {
#pragma unroll
    for (int b = 0; b < 8; ++b) acc[b] += __shfl_xor(acc[b], off, 64);
  }
  if (l < 8) d[l * 512 + co] = rsqrtf(acc[l] + 1e-8f);
}

// ---------------- kernel 4: xs prep: NCHW f32 -> padded NHWC bf16, x * s ----------------
__global__ __launch_bounds__(256) void xs_kernel(const float* __restrict__ x,
                                                 const float* __restrict__ s,
                                                 __hip_bfloat16* __restrict__ xsp) {
  // grid: b(8) * h(32) * cc(8) = 2048 blocks of 256
  int bid = blockIdx.x;
  int cc = bid & 7;
  int h = (bid >> 3) & 31;
  int b = bid >> 8;
  int tid = threadIdx.x;
  __shared__ __hip_bfloat16 tile[32][72];  // [w][ci_local], padded

  int cil = tid >> 2;            // 0..63
  int w0 = (tid & 3) * 8;        // 0,8,16,24
  int ci = cc * 64 + cil;
  const float* xp = x + (((size_t)(b * 512 + ci) * 32 + h) << 5) + w0;
  float sv = s[b * 512 + ci];
  float4 a0 = *reinterpret_cast<const float4*>(xp);
  float4 a1 = *reinterpret_cast<const float4*>(xp + 4);
  tile[w0 + 0][cil] = __float2bfloat16(a0.x * sv);
  tile[w0 + 1][cil] = __float2bfloat16(a0.y * sv);
  tile[w0 + 2][cil] = __float2bfloat16(a0.z * sv);
  tile[w0 + 3][cil] = __float2bfloat16(a0.w * sv);
  tile[w0 + 4][cil] = __float2bfloat16(a1.x * sv);
  tile[w0 + 5][cil] = __float2bfloat16(a1.y * sv);
  tile[w0 + 6][cil] = __float2bfloat16(a1.z * sv);
  tile[w0 + 7][cil] = __float2bfloat16(a1.w * sv);
  __syncthreads();

  int wloc = tid >> 3;           // 0..31
  int cj = (tid & 7) * 8;        // 0..56
  int4 v = *reinterpret_cast<const int4*>(&tile[wloc][cj]);
  unsigned off = (unsigned)((b * 34 + h + 1) * 34 + (wloc + 1)) * 512 + cc * 64 + cj;
  *reinterpret_cast<int4*>(xsp + off) = v;
}

// ---------------- kernel 5: conv — halo implicit GEMM, 8 waves, K-split ----------------
// 128pix x 128co tile, 512 threads. Waves: kg = wv>>2 owns K-half (32 of 64 ci/chunk);
// (wr,wc) = ((wv>>1)&1, wv&1) 2x2 grid, each wave 64pix x 64co, acc[4][4].
// A-halo (6x34 rows x 64ci) double-buffered; B (128co x 64ci) triple-buffered,
// distance-2 counted prefetch. Cross-kg reduction via LDS at the end.
__global__ __launch_bounds__(512, 2) void conv_kernel(const __hip_bfloat16* __restrict__ xsp,
                                                      const __hip_bfloat16* __restrict__ wt,
                                                      const float* __restrict__ dmod,
                                                      float* __restrict__ out) {
  __shared__ __hip_bfloat16 As_[2][256 * 64];  // 2 x 32 KB (204 halo rows used)
  __shared__ __hip_bfloat16 Bs_[3][128 * 64];  // 3 x 16 KB
  const int bid = blockIdx.x;  // 256 blocks
  const int xcd = bid & 7, slot = bid >> 3;    // XCD-aware remap
  const int bm = xcd * 8 + (slot >> 2);
  const int bn = slot & 3;
  const int tid = threadIdx.x;
  const int wv = tid >> 6;
  const int l = tid & 63;
  const int kg = wv >> 2;          // K-group
  const int wr = (wv >> 1) & 1, wc = wv & 1;
  const int bb = bm >> 3;          // batch
  const int h0 = (bm & 7) << 2;    // first output image row of tile

  const int swz = (((l & 7) ^ (l >> 3)) << 3);  // staging pre-swizzle (row&7 == l>>3)
  unsigned boff[2];
#pragma unroll
  for (int j = 0; j < 2; ++j) {
    int row = ((j * 8 + wv) << 3) + (l >> 3);
    boff[j] = (unsigned)((bn << 7) + row) * 512 + swz;
  }
  unsigned ahoff[4];
#pragma unroll
  for (int j = 0; j < 4; ++j) {
    int r = j * 64 + wv * 8 + (l >> 3);  // 0..255; rows 204..255 clamp (never read)
    int rc = r > 203 ? 203 : r;
    int hr = rc / 34, hc = rc - hr * 34;
    ahoff[j] = (unsigned)((bb * 34 + h0 + hr) * 34 + hc) * 512 + swz;
  }
  int pb[4];
#pragma unroll
  for (int m = 0; m < 4; ++m)
    pb[m] = ((wr << 1) + (m >> 1)) * 34 + ((m & 1) << 4) + (l & 15);

  f32x4 acc[4][4];
#pragma unroll
  for (int n = 0; n < 4; ++n)
#pragma unroll
    for (int m = 0; m < 4; ++m) acc[n][m] = (f32x4)0.f;

  auto stageB = [&](__hip_bfloat16* Bn, int t, int k0c) {
    const __hip_bfloat16* src = wt + t * 262144 + k0c * 64;
#pragma unroll
    for (int j = 0; j < 2; ++j)
      GLL(src + boff[j], Bn + ((j * 8 + wv) << 9));
  };
  auto stageA1 = [&](__hip_bfloat16* An, int j, int kn) {
    GLL(xsp + ahoff[j] + kn * 64, An + ((j * 64 + wv * 8) << 6));
  };
  auto phase = [&](const __hip_bfloat16* Aq, const __hip_bfloat16* Bq, int dh, int dw) {
    const int cb = (kg << 2) + (l >> 4);
    bf16x8 af[4], bfr[4];
#pragma unroll
    for (int m = 0; m < 4; ++m) {
      int p = pb[m] + dh * 34 + dw;
      af[m] = *reinterpret_cast<const bf16x8*>(Aq + p * 64 + ((cb ^ (p & 7)) << 3));
    }
#pragma unroll
    for (int n = 0; n < 4; ++n) {
      int row = (wc << 6) + (n << 4) + (l & 15);
      bfr[n] = *reinterpret_cast<const bf16x8*>(Bq + row * 64 + ((cb ^ (l & 7)) << 3));
    }
#pragma unroll
    for (int n = 0; n < 4; ++n)
#pragma unroll
      for (int m = 0; m < 4; ++m)
        acc[n][m] = __builtin_amdgcn_mfma_f32_16x16x32_bf16(bfr[n], af[m], acc[n][m], 0, 0, 0);
  };

#define SB0 __builtin_amdgcn_sched_barrier(0)
#define WAITBAR(N)                                          \
  asm volatile("s_waitcnt vmcnt(" #N ")" ::: "memory");     \
  __builtin_amdgcn_s_barrier();                             \
  SB0

  // prologue: A chunks (k=0) then B taps 0,1 — queue = [a0..a3, b0x2, b1x2]
#pragma unroll
  for (int j = 0; j < 4; ++j) stageA1(&As_[0][0], j, 0);
  SB0;
  stageB(&Bs_[0][0], 0, 0);
  stageB(&Bs_[1][0], 1, 0);

#pragma unroll 1
  for (int k0 = 0; k0 < 7; ++k0) {  // steady chunks
    const __hip_bfloat16* Aq = &As_[k0 & 1][0];
    __hip_bfloat16* An = &As_[(k0 + 1) & 1][0];
    WAITBAR(2); stageB(&Bs_[2][0], 2, k0); SB0; stageA1(An, 0, k0 + 1); SB0;
    phase(Aq, &Bs_[0][0], 0, 0);
    WAITBAR(3); stageB(&Bs_[0][0], 3, k0); SB0; stageA1(An, 1, k0 + 1); SB0;
    phase(Aq, &Bs_[1][0], 0, 1);
    WAITBAR(4); stageB(&Bs_[1][0], 4, k0); SB0; stageA1(An, 2, k0 + 1); SB0;
    phase(Aq, &Bs_[2][0], 0, 2);
    WAITBAR(4); stageB(&Bs_[2][0], 5, k0); SB0; stageA1(An, 3, k0 + 1); SB0;
    phase(Aq, &Bs_[0][0], 1, 0);
    WAITBAR(4); stageB(&Bs_[0][0], 6, k0); SB0;
    phase(Aq, &Bs_[1][0], 1, 1);
    WAITBAR(3); stageB(&Bs_[1][0], 7, k0); SB0;
    phase(Aq, &Bs_[2][0], 1, 2);
    WAITBAR(2); stageB(&Bs_[2][0], 8, k0); SB0;
    phase(Aq, &Bs_[0][0], 2, 0);
    WAITBAR(2); stageB(&Bs_[0][0], 0, k0 + 1); SB0;
    phase(Aq, &Bs_[1][0], 2, 1);
    WAITBAR(2); stageB(&Bs_[1][0], 1, k0 + 1); SB0;
    phase(Aq, &Bs_[2][0], 2, 2);
  }
  {  // drain chunk k0 = 7
    const __hip_bfloat16* Aq = &As_[1][0];
    WAITBAR(2); stageB(&Bs_[2][0], 2, 7); SB0; phase(Aq, &Bs_[0][0], 0, 0);
    WAITBAR(2); stageB(&Bs_[0][0], 3, 7); SB0; phase(Aq, &Bs_[1][0], 0, 1);
    WAITBAR(2); stageB(&Bs_[1][0], 4, 7); SB0; phase(Aq, &Bs_[2][0], 0, 2);
    WAITBAR(2); stageB(&Bs_[2][0], 5, 7); SB0; phase(Aq, &Bs_[0][0], 1, 0);
    WAITBAR(2); stageB(&Bs_[0][0], 6, 7); SB0; phase(Aq, &Bs_[1][0], 1, 1);
    WAITBAR(2); stageB(&Bs_[1][0], 7, 7); SB0; phase(Aq, &Bs_[2][0], 1, 2);
    WAITBAR(2); stageB(&Bs_[2][0], 8, 7); SB0; phase(Aq, &Bs_[0][0], 2, 0);
    WAITBAR(2); phase(Aq, &Bs_[1][0], 2, 1);
    WAITBAR(0); phase(Aq, &Bs_[2][0], 2, 2);
  }
#undef WAITBAR
#undef SB0

  // ---- cross-kg reduction via LDS (SoA: chunk i -> [4 waves][64 lanes] f32x4) ----
  float* red = reinterpret_cast<float*>(&As_[0][0]);  // 64 KB, A-reads all consumed
  __syncthreads();
  if (kg == 1) {
#pragma unroll
    for (int n = 0; n < 4; ++n)
#pragma unroll
      for (int m = 0; m < 4; ++m)
        *reinterpret_cast<f32x4*>(red + (n * 4 + m) * 1024 + (wv & 3) * 256 + l * 4) =
            acc[n][m];
  }
  __syncthreads();
  if (kg == 0) {
    const int pixbase = ((bm & 7) << 7) + (wr << 6) + (l & 15);
    const int cob = (bn << 7) + (wc << 6) + ((l >> 4) << 2);
    float* ob = out + ((size_t)bb << 19);
    const float* drow = dmod + bb * 512;
#pragma unroll
    for (int n = 0; n < 4; ++n) {
#pragma unroll
      for (int m = 0; m < 4; ++m)
        acc[n][m] += *reinterpret_cast<const f32x4*>(red + (n * 4 + m) * 1024 + wv * 256 + l * 4);
#pragma unroll
      for (int jj = 0; jj < 4; ++jj) {
        const int co = cob + (n << 4) + jj;
        const float dv = drow[co];
        float* orow = ob + ((unsigned)co << 10) + pixbase;
#pragma unroll
        for (int m = 0; m < 4; ++m) orow[m << 4] = acc[n][m][jj] * dv;
      }
    }
  }
}

extern "C" void kernel_launch(void* const* d_in, const int* in_sizes, int n_in,
                              void* d_out, int out_size, void* d_ws, size_t ws_size,
                              hipStream_t stream) {
  (void)in_sizes; (void)n_in; (void)out_size; (void)ws_size;
  const float* x = (const float*)d_in[0];       // [8,512,32,32]
  const float* y = (const float*)d_in[1];       // [8,512]
  const float* w = (const float*)d_in[2];       // [512,512,3,3]
  const float* mw = (const float*)d_in[3];      // [512,512]
  const float* bias = (const float*)d_in[4];    // [512]
  float* out = (float*)d_out;                   // [8,512,32,32]

  char* ws = (char*)d_ws;
  float* s = (float*)(ws + 0);                  // 16 KB
  float* dmod = (float*)(ws + 16384);           // 16 KB
  float* wsq = (float*)(ws + 32768);            // 1 MB
  __hip_bfloat16* wt = (__hip_bfloat16*)(ws + 1081344);    // 9*512*512*2 = 4.5 MB
  __hip_bfloat16* xsp = (__hip_bfloat16*)(ws + 5799936);   // 8*34*34*512*2 = 9.03 MB

  hipMemsetAsync(xsp, 0, 9469952, stream);  // zero padded borders
  style_kernel<<<512, 64, 0, stream>>>(y, mw, bias, s);
  wprep_kernel<<<1024, 256, 0, stream>>>(w, wt, wsq);
  demod_kernel<<<512, 64, 0, stream>>>(wsq, s, dmod);
  xs_kernel<<<2048, 256, 0, stream>>>(x, s, xsp);
  conv_kernel<<<256, 512, 0, stream>>>(xsp, wt, dmod, out);
}